// Round 1
// baseline (659.778 us; speedup 1.0000x reference)
//
#include <hip/hip_runtime.h>
#include <hip/hip_bf16.h>
#include <cstdint>

#define B_ 16
#define C_ 256
#define CQ 32
#define H_ 96
#define W_ 96
#define HW 9216
#define NBAND 32

typedef unsigned short u16;
typedef short bf16x8 __attribute__((ext_vector_type(8)));
typedef float f32x4 __attribute__((ext_vector_type(4)));

__device__ inline u16 f2bf(float f) {
    uint32_t u = __float_as_uint(f);
    u += 0x7FFF + ((u >> 16) & 1);   // RNE
    return (u16)(u >> 16);
}
__device__ inline float bf2f(u16 s) {
    return __uint_as_float(((uint32_t)s) << 16);
}

// ---------------- Kernel 1: transpose + cast  x[b][c][s] f32 -> xT[b][s][c] bf16
__global__ __launch_bounds__(256) void xpose_kernel(const float* __restrict__ x,
                                                    u16* __restrict__ xT) {
    __shared__ float tile[64][65];
    int s0 = blockIdx.x * 64;
    int c0 = blockIdx.y * 64;
    int b  = blockIdx.z;
    int t = threadIdx.x;

    const float* xb = x + ((size_t)b * C_ + c0) * HW + s0;
    int j = t & 63, i0 = t >> 6;
    #pragma unroll
    for (int ii = 0; ii < 16; ++ii) {
        int i = i0 * 16 + ii;
        tile[i][j] = xb[(size_t)i * HW + j];
    }
    __syncthreads();
    u16* xtb = xT + ((size_t)b * HW + s0) * C_ + c0;
    int i = t & 63, j0 = t >> 6;
    #pragma unroll
    for (int jj = 0; jj < 16; ++jj) {
        int jw = j0 * 16 + jj;
        xtb[(size_t)jw * C_ + i] = f2bf(tile[i][jw]);
    }
}

// ---------------- Kernel 2: qkv GEMM.  out[m][s] = sum_k W[m][k] * x[k][s] + bias[m]
// M = 320 (0..31 q, 32..63 k, 64..319 v), per batch N = 9216, K = 256.
// BM=64, BN=128, BK=32. 4 waves, each wave: 64m x 32n.
__global__ __launch_bounds__(256) void qkv_gemm_kernel(
    const u16* __restrict__ xT,
    const float* __restrict__ Wq, const float* __restrict__ bq,
    const float* __restrict__ Wk, const float* __restrict__ bk,
    const float* __restrict__ Wv, const float* __restrict__ bv,
    u16* __restrict__ qws, u16* __restrict__ kws,
    float* __restrict__ vout)
{
    __shared__ u16 lA[64 * 32];
    __shared__ u16 lB[128 * 32];

    int s0 = blockIdx.x * 128;
    int m0 = blockIdx.y * 64;
    int b  = blockIdx.z;
    int t  = threadIdx.x;
    int w  = t >> 6, l = t & 63;
    int lr = l & 15, lg = l >> 4;

    f32x4 acc[4][2] = {};

    // A staging assignment: thread -> (row ai, k-octet ak)
    int ai = t >> 2;
    int ak = (t & 3) * 8;
    int arow = m0 + ai;
    const float* wrow = (arow < 32) ? (Wq + arow * 256)
                      : (arow < 64) ? (Wk + (arow - 32) * 256)
                                    : (Wv + (arow - 64) * 256);
    // B staging: thread -> (n row bn, 16-elem half bk8)
    int bn  = t >> 1;
    int bk8 = (t & 1) * 16;
    const u16* xrow = xT + ((size_t)b * HW + s0 + bn) * C_ + bk8;

    for (int k0 = 0; k0 < 256; k0 += 32) {
        {   // stage A (f32 -> bf16)
            const float* p = wrow + k0 + ak;
            float4 f0 = *reinterpret_cast<const float4*>(p);
            float4 f1 = *reinterpret_cast<const float4*>(p + 4);
            uint4 pk;
            pk.x = f2bf(f0.x) | ((uint32_t)f2bf(f0.y) << 16);
            pk.y = f2bf(f0.z) | ((uint32_t)f2bf(f0.w) << 16);
            pk.z = f2bf(f1.x) | ((uint32_t)f2bf(f1.y) << 16);
            pk.w = f2bf(f1.z) | ((uint32_t)f2bf(f1.w) << 16);
            *reinterpret_cast<uint4*>(&lA[ai * 32 + ak]) = pk;
        }
        {   // stage B (already bf16, k-contiguous thanks to xT)
            const uint4* p = reinterpret_cast<const uint4*>(xrow + k0);
            uint4 v0 = p[0], v1 = p[1];
            uint4* d = reinterpret_cast<uint4*>(&lB[bn * 32 + bk8]);
            d[0] = v0; d[1] = v1;
        }
        __syncthreads();
        bf16x8 bfr[2];
        bfr[0] = *reinterpret_cast<const bf16x8*>(&lB[(w * 32 + lr) * 32 + lg * 8]);
        bfr[1] = *reinterpret_cast<const bf16x8*>(&lB[(w * 32 + 16 + lr) * 32 + lg * 8]);
        #pragma unroll
        for (int mf = 0; mf < 4; ++mf) {
            bf16x8 af = *reinterpret_cast<const bf16x8*>(&lA[(mf * 16 + lr) * 32 + lg * 8]);
            acc[mf][0] = __builtin_amdgcn_mfma_f32_16x16x32_bf16(af, bfr[0], acc[mf][0], 0, 0, 0);
            acc[mf][1] = __builtin_amdgcn_mfma_f32_16x16x32_bf16(af, bfr[1], acc[mf][1], 0, 0, 0);
        }
        __syncthreads();
    }

    // epilogue: D row = 4*lg + r_reg (+ mf*16), col = lr (+ nf*16)
    #pragma unroll
    for (int mf = 0; mf < 4; ++mf) {
        #pragma unroll
        for (int r = 0; r < 4; ++r) {
            int mg = m0 + mf * 16 + lg * 4 + r;
            float bias = (mg < 32) ? bq[mg] : (mg < 64) ? bk[mg - 32] : bv[mg - 64];
            #pragma unroll
            for (int nf = 0; nf < 2; ++nf) {
                int s = s0 + w * 32 + nf * 16 + lr;
                float val = acc[mf][nf][r] + bias;
                if (mg < 32) {
                    qws[((size_t)b * CQ + mg) * HW + s] = f2bf(val);
                } else if (mg < 64) {
                    kws[((size_t)b * CQ + (mg - 32)) * HW + s] = f2bf(val);
                } else {
                    vout[((size_t)b * C_ + (mg - 64)) * HW + s] = val;
                }
            }
        }
    }
}

// ---------------- Kernel 3: per (b, band) attention + apply (+ residual), in-place over v
__global__ __launch_bounds__(256) void attn_kernel(
    const float* __restrict__ x,
    const u16* __restrict__ qws, const u16* __restrict__ kws,
    const float* __restrict__ gamma,
    float* __restrict__ out)   // holds v on entry for this block's band
{
    __shared__ __align__(16) u16 qkl[2 * CQ * 288];  // ql then kl; front reused as vl (f32)
    __shared__ float ah[96 * 9];   // [w][kk][j]
    __shared__ float av[96 * 9];   // [(r*32+nw)][kk][jw]
    float* vl = reinterpret_cast<float*>(qkl);       // 2304 f32 = 9216 B << 36 KB

    int n = blockIdx.x;
    int b = blockIdx.y;
    int t = threadIdx.x;
    float g = gamma[0];

    u16* ql = qkl;
    u16* kl = qkl + CQ * 288;

    size_t qbase = (size_t)b * CQ * HW + (size_t)n * 288;
    for (int e = t; e < CQ * 288; e += 256) {
        int cq = e / 288, off = e - cq * 288;
        ql[e] = qws[qbase + (size_t)cq * HW + off];
        kl[e] = kws[qbase + (size_t)cq * HW + off];
    }
    __syncthreads();

    for (int item = t; item < 576; item += 256) {
        if (item < 288) {
            // horizontal: fixed (w, kk); logits over j = key row in band
            int w = item % 96, kk = item / 96;
            float l0 = 0.f, l1 = 0.f, l2 = 0.f;
            for (int c = 0; c < CQ; ++c) {
                float qv = bf2f(ql[c * 288 + kk * 96 + w]);
                l0 += qv * bf2f(kl[c * 288 + w]);
                l1 += qv * bf2f(kl[c * 288 + 96 + w]);
                l2 += qv * bf2f(kl[c * 288 + 192 + w]);
            }
            float m = fmaxf(fmaxf(l0, l1), l2);
            float e0 = __expf(l0 - m), e1 = __expf(l1 - m), e2 = __expf(l2 - m);
            float inv = 1.0f / (e0 + e1 + e2);
            ah[(w * 3 + kk) * 3 + 0] = e0 * inv;
            ah[(w * 3 + kk) * 3 + 1] = e1 * inv;
            ah[(w * 3 + kk) * 3 + 2] = e2 * inv;
        } else {
            // vertical: fixed (row r, band nw, kk); logits over j = key col in band
            int it = item - 288;
            int r = it / 96, c2 = it - r * 96;
            int nw = c2 / 3, kk = c2 - nw * 3;
            int base = r * 96 + nw * 3;
            float l0 = 0.f, l1 = 0.f, l2 = 0.f;
            for (int c = 0; c < CQ; ++c) {
                float qv = bf2f(ql[c * 288 + base + kk]);
                l0 += qv * bf2f(kl[c * 288 + base + 0]);
                l1 += qv * bf2f(kl[c * 288 + base + 1]);
                l2 += qv * bf2f(kl[c * 288 + base + 2]);
            }
            float m = fmaxf(fmaxf(l0, l1), l2);
            float e0 = __expf(l0 - m), e1 = __expf(l1 - m), e2 = __expf(l2 - m);
            float inv = 1.0f / (e0 + e1 + e2);
            av[(r * 32 + nw) * 9 + kk * 3 + 0] = e0 * inv;
            av[(r * 32 + nw) * 9 + kk * 3 + 1] = e1 * inv;
            av[(r * 32 + nw) * 9 + kk * 3 + 2] = e2 * inv;
        }
    }
    __syncthreads();

    size_t vbase = (size_t)b * C_ * HW + (size_t)n * 288;
    for (int c0 = 0; c0 < C_; c0 += 8) {
        for (int e = t; e < 2304; e += 256) {
            int c = e / 288, off = e - c * 288;
            vl[e] = out[vbase + (size_t)(c0 + c) * HW + off];
        }
        __syncthreads();
        for (int e = t; e < 2304; e += 256) {
            int c = e / 288, off = e - c * 288;
            int r = off / 96, w = off - r * 96;
            float oh = vl[c * 288 + w]        * ah[w * 9 + 0 + r]
                     + vl[c * 288 + 96 + w]   * ah[w * 9 + 3 + r]
                     + vl[c * 288 + 192 + w]  * ah[w * 9 + 6 + r];
            int nw = w / 3, jw = w - nw * 3;
            const float* avp = &av[(r * 32 + nw) * 9];
            float ov = vl[c * 288 + r * 96 + nw * 3 + 0] * avp[0 + jw]
                     + vl[c * 288 + r * 96 + nw * 3 + 1] * avp[3 + jw]
                     + vl[c * 288 + r * 96 + nw * 3 + 2] * avp[6 + jw];
            size_t gidx = vbase + (size_t)(c0 + c) * HW + off;
            out[gidx] = g * (oh + ov) + x[gidx];
        }
        __syncthreads();
    }
}

extern "C" void kernel_launch(void* const* d_in, const int* in_sizes, int n_in,
                              void* d_out, int out_size, void* d_ws, size_t ws_size,
                              hipStream_t stream) {
    const float* x     = (const float*)d_in[0];
    const float* Wq    = (const float*)d_in[1];
    const float* bq    = (const float*)d_in[2];
    const float* Wk    = (const float*)d_in[3];
    const float* bk    = (const float*)d_in[4];
    const float* Wv    = (const float*)d_in[5];
    const float* bv    = (const float*)d_in[6];
    const float* gamma = (const float*)d_in[7];
    float* out = (float*)d_out;

    u16* xT  = (u16*)d_ws;                                   // B*HW*C bf16  (75.5 MB)
    u16* qws = xT + (size_t)B_ * HW * C_;                    // B*CQ*HW bf16 ( 9.4 MB)
    u16* kws = qws + (size_t)B_ * CQ * HW;                   // B*CQ*HW bf16 ( 9.4 MB)

    xpose_kernel<<<dim3(HW / 64, C_ / 64, B_), 256, 0, stream>>>(x, xT);
    qkv_gemm_kernel<<<dim3(HW / 128, 5, B_), 256, 0, stream>>>(
        xT, Wq, bq, Wk, bk, Wv, bv, qws, kws, out);
    attn_kernel<<<dim3(NBAND, B_), 256, 0, stream>>>(x, qws, kws, gamma, out);
}

// Round 2
// 488.082 us; speedup vs baseline: 1.3518x; 1.3518x over previous
//
#include <hip/hip_runtime.h>
#include <hip/hip_bf16.h>
#include <cstdint>

#define B_ 16
#define C_ 256
#define CQ 32
#define H_ 96
#define W_ 96
#define HW 9216
#define NBAND 32

typedef unsigned short u16;
typedef short bf16x8 __attribute__((ext_vector_type(8)));
typedef float f32x4 __attribute__((ext_vector_type(4)));

__device__ inline u16 f2bf(float f) {
    uint32_t u = __float_as_uint(f);
    u += 0x7FFF + ((u >> 16) & 1);   // RNE
    return (u16)(u >> 16);
}
__device__ inline float bf2f(u16 s) {
    return __uint_as_float(((uint32_t)s) << 16);
}

__device__ inline void gload_lds16(const void* g, void* l) {
    __builtin_amdgcn_global_load_lds(
        (const __attribute__((address_space(1))) uint32_t*)g,
        (__attribute__((address_space(3))) uint32_t*)l, 16, 0, 0);
}

// ---------------- Kernel 1: transpose + cast  x[b][c][s] f32 -> xT[b][s][c] bf16
__global__ __launch_bounds__(256) void xpose_kernel(const float* __restrict__ x,
                                                    u16* __restrict__ xT) {
    __shared__ float tile[64][65];
    int s0 = blockIdx.x * 64;
    int c0 = blockIdx.y * 64;
    int b  = blockIdx.z;
    int t = threadIdx.x;

    const float* xb = x + ((size_t)b * C_ + c0) * HW + s0;
    int j = t & 63, i0 = t >> 6;
    #pragma unroll
    for (int ii = 0; ii < 16; ++ii) {
        int i = i0 * 16 + ii;
        tile[i][j] = xb[(size_t)i * HW + j];
    }
    __syncthreads();
    u16* xtb = xT + ((size_t)b * HW + s0) * C_ + c0;
    int i = t & 63, j0 = t >> 6;
    #pragma unroll
    for (int jj = 0; jj < 16; ++jj) {
        int jw = j0 * 16 + jj;
        xtb[(size_t)jw * C_ + i] = f2bf(tile[i][jw]);
    }
}

// ---------------- Kernel 2: qkv GEMM.  out[m][s] = sum_k W[m][k] * xT[s][k] + bias[m]
// M = 320 (0..31 q, 32..63 k, 64..319 v), per batch N = 9216, K = 256.
// BM=64, BN=256, BK=64. 4 waves; wave w owns n-cols [64w, 64w+64).
// LDS rows are 128B (64 bf16); 16B chunk c of row r stored at chunk c^(r&7) (XOR swizzle).
__global__ __launch_bounds__(256) void qkv_gemm_kernel(
    const u16* __restrict__ xT,
    const float* __restrict__ Wq, const float* __restrict__ bq,
    const float* __restrict__ Wk, const float* __restrict__ bk,
    const float* __restrict__ Wv, const float* __restrict__ bv,
    u16* __restrict__ qws, u16* __restrict__ kws,
    float* __restrict__ vout)
{
    __shared__ u16 lA[64 * 64];    // 8 KB
    __shared__ u16 lB[256 * 64];   // 32 KB

    int s0 = blockIdx.x * 256;
    int m0 = blockIdx.y * 64;
    int b  = blockIdx.z;
    int t  = threadIdx.x;
    int w  = t >> 6, l = t & 63;
    int lr = l & 15, lg = l >> 4;

    f32x4 acc[4][4] = {};

    // A staging: thread t -> row ar, two 16B chunks starting at chunk (t&3)*2
    int ar = t >> 2;
    int ac = (t & 3) * 2;          // chunk index (16 bf16 elems = 2 chunks per thread)
    int arow = m0 + ar;
    const float* wrow = (arow < 32) ? (Wq + arow * 256)
                      : (arow < 64) ? (Wk + (arow - 32) * 256)
                                    : (Wv + (arow - 64) * 256);

    // B staging via global_load_lds: wave w, issue i covers tile rows [64w+8i, 64w+8i+8)
    int rb_sub = l >> 3;           // 0..7 row within an 8-row group
    int cb     = l & 7;            // chunk within row
    const char* gB = (const char*)(xT + ((size_t)b * HW + s0) * C_);

    for (int k0 = 0; k0 < 256; k0 += 64) {
        {   // stage A (f32 -> bf16, swizzled ds_write)
            const float* p = wrow + k0 + (t & 3) * 16;
            float4 f0 = *reinterpret_cast<const float4*>(p);
            float4 f1 = *reinterpret_cast<const float4*>(p + 4);
            float4 f2 = *reinterpret_cast<const float4*>(p + 8);
            float4 f3 = *reinterpret_cast<const float4*>(p + 12);
            uint4 pk0, pk1;
            pk0.x = f2bf(f0.x) | ((uint32_t)f2bf(f0.y) << 16);
            pk0.y = f2bf(f0.z) | ((uint32_t)f2bf(f0.w) << 16);
            pk0.z = f2bf(f1.x) | ((uint32_t)f2bf(f1.y) << 16);
            pk0.w = f2bf(f1.z) | ((uint32_t)f2bf(f1.w) << 16);
            pk1.x = f2bf(f2.x) | ((uint32_t)f2bf(f2.y) << 16);
            pk1.y = f2bf(f2.z) | ((uint32_t)f2bf(f2.w) << 16);
            pk1.z = f2bf(f3.x) | ((uint32_t)f2bf(f3.y) << 16);
            pk1.w = f2bf(f3.z) | ((uint32_t)f2bf(f3.w) << 16);
            char* lab = (char*)lA + ar * 128;
            *reinterpret_cast<uint4*>(lab + ((ac    ) ^ (ar & 7)) * 16) = pk0;
            *reinterpret_cast<uint4*>(lab + ((ac + 1) ^ (ar & 7)) * 16) = pk1;
        }
        {   // stage B: 8 issues per wave, each 8 rows x 128B
            #pragma unroll
            for (int i = 0; i < 8; ++i) {
                int rb = w * 64 + i * 8 + rb_sub;              // tile row = s offset
                const char* src = gB + ((size_t)rb * C_ + k0) * 2 + ((cb ^ (rb & 7)) * 16);
                char* dst = (char*)lB + (w * 64 + i * 8) * 128;
                gload_lds16(src, dst);
            }
        }
        __syncthreads();

        #pragma unroll
        for (int ss = 0; ss < 2; ++ss) {
            bf16x8 af[4], bf[4];
            #pragma unroll
            for (int mf = 0; mf < 4; ++mf) {
                int r = mf * 16 + lr;
                af[mf] = *reinterpret_cast<const bf16x8*>(
                    (char*)lA + r * 128 + (((ss * 4 + lg) ^ (lr & 7)) * 16));
            }
            #pragma unroll
            for (int nf = 0; nf < 4; ++nf) {
                int r = w * 64 + nf * 16 + lr;
                bf[nf] = *reinterpret_cast<const bf16x8*>(
                    (char*)lB + r * 128 + (((ss * 4 + lg) ^ (lr & 7)) * 16));
            }
            #pragma unroll
            for (int mf = 0; mf < 4; ++mf)
                #pragma unroll
                for (int nf = 0; nf < 4; ++nf)
                    acc[mf][nf] = __builtin_amdgcn_mfma_f32_16x16x32_bf16(
                        af[mf], bf[nf], acc[mf][nf], 0, 0, 0);
        }
        __syncthreads();
    }

    // epilogue: D row = mf*16 + lg*4 + r, col = w*64 + nf*16 + lr
    #pragma unroll
    for (int mf = 0; mf < 4; ++mf) {
        #pragma unroll
        for (int r = 0; r < 4; ++r) {
            int mg = m0 + mf * 16 + lg * 4 + r;
            float bias = (mg < 32) ? bq[mg] : (mg < 64) ? bk[mg - 32] : bv[mg - 64];
            #pragma unroll
            for (int nf = 0; nf < 4; ++nf) {
                int s = s0 + w * 64 + nf * 16 + lr;
                float val = acc[mf][nf][r] + bias;
                if (mg < 32) {
                    qws[((size_t)b * CQ + mg) * HW + s] = f2bf(val);
                } else if (mg < 64) {
                    kws[((size_t)b * CQ + (mg - 32)) * HW + s] = f2bf(val);
                } else {
                    vout[((size_t)b * C_ + (mg - 64)) * HW + s] = val;
                }
            }
        }
    }
}

// ---------------- Kernel 3a: per (b, band) attention weights -> wbuf
// wbuf[(b*32+n)*1728 + 0..863]   = ah[(w*3+kk)*3 + j]
// wbuf[(b*32+n)*1728 + 864..]    = av[(r*32+nw)*9 + kk*3 + jw]
__global__ __launch_bounds__(256) void attnw_kernel(
    const u16* __restrict__ qws, const u16* __restrict__ kws,
    float* __restrict__ wbuf)
{
    __shared__ __align__(16) u16 qkl[2 * CQ * 288];
    int n = blockIdx.x;
    int b = blockIdx.y;
    int t = threadIdx.x;

    u16* ql = qkl;
    u16* kl = qkl + CQ * 288;
    float* gw = wbuf + ((size_t)(b * NBAND + n)) * 1728;

    size_t qbase = (size_t)b * CQ * HW + (size_t)n * 288;
    for (int e = t; e < CQ * 288; e += 256) {
        int cq = e / 288, off = e - cq * 288;
        ql[e] = qws[qbase + (size_t)cq * HW + off];
        kl[e] = kws[qbase + (size_t)cq * HW + off];
    }
    __syncthreads();

    for (int item = t; item < 576; item += 256) {
        if (item < 288) {
            int w = item % 96, kk = item / 96;
            float l0 = 0.f, l1 = 0.f, l2 = 0.f;
            for (int c = 0; c < CQ; ++c) {
                float qv = bf2f(ql[c * 288 + kk * 96 + w]);
                l0 += qv * bf2f(kl[c * 288 + w]);
                l1 += qv * bf2f(kl[c * 288 + 96 + w]);
                l2 += qv * bf2f(kl[c * 288 + 192 + w]);
            }
            float m = fmaxf(fmaxf(l0, l1), l2);
            float e0 = __expf(l0 - m), e1 = __expf(l1 - m), e2 = __expf(l2 - m);
            float inv = 1.0f / (e0 + e1 + e2);
            gw[(w * 3 + kk) * 3 + 0] = e0 * inv;
            gw[(w * 3 + kk) * 3 + 1] = e1 * inv;
            gw[(w * 3 + kk) * 3 + 2] = e2 * inv;
        } else {
            int it = item - 288;
            int r = it / 96, c2 = it - r * 96;
            int nw = c2 / 3, kk = c2 - nw * 3;
            int base = r * 96 + nw * 3;
            float l0 = 0.f, l1 = 0.f, l2 = 0.f;
            for (int c = 0; c < CQ; ++c) {
                float qv = bf2f(ql[c * 288 + base + kk]);
                l0 += qv * bf2f(kl[c * 288 + base + 0]);
                l1 += qv * bf2f(kl[c * 288 + base + 1]);
                l2 += qv * bf2f(kl[c * 288 + base + 2]);
            }
            float m = fmaxf(fmaxf(l0, l1), l2);
            float e0 = __expf(l0 - m), e1 = __expf(l1 - m), e2 = __expf(l2 - m);
            float inv = 1.0f / (e0 + e1 + e2);
            float* avp = gw + 864 + (r * 32 + nw) * 9 + kk * 3;
            avp[0] = e0 * inv;
            avp[1] = e1 * inv;
            avp[2] = e2 * inv;
        }
    }
}

// ---------------- Kernel 3b: apply. One block per (b, band, 8-channel chunk).
__global__ __launch_bounds__(256) void apply_kernel(
    const float* __restrict__ x,
    const float* __restrict__ wbuf,
    const float* __restrict__ gamma,
    float* __restrict__ out)   // holds v on entry for this block's region
{
    __shared__ float wsh[1728];     // ah [0,864), av [864,1728)
    __shared__ float vl[2304];
    int cc = blockIdx.x;            // channel chunk (8 ch)
    int n  = blockIdx.y;
    int b  = blockIdx.z;
    int t  = threadIdx.x;
    float g = gamma[0];

    const float* gw = wbuf + ((size_t)(b * NBAND + n)) * 1728;
    for (int e = t; e < 1728; e += 256) wsh[e] = gw[e];

    size_t vbase = (size_t)b * C_ * HW + (size_t)(cc * 8) * HW + (size_t)n * 288;
    for (int e = t; e < 2304; e += 256) {
        int c = e / 288, off = e - c * 288;
        vl[e] = out[vbase + (size_t)c * HW + off];
    }
    __syncthreads();

    const float* ah = wsh;
    const float* av = wsh + 864;
    for (int e = t; e < 2304; e += 256) {
        int c = e / 288, off = e - c * 288;
        int r = off / 96, w = off - r * 96;
        float oh = vl[c * 288 + w]        * ah[w * 9 + 0 + r]
                 + vl[c * 288 + 96 + w]   * ah[w * 9 + 3 + r]
                 + vl[c * 288 + 192 + w]  * ah[w * 9 + 6 + r];
        int nw = w / 3, jw = w - nw * 3;
        const float* avp = &av[(r * 32 + nw) * 9];
        float ov = vl[c * 288 + r * 96 + nw * 3 + 0] * avp[0 + jw]
                 + vl[c * 288 + r * 96 + nw * 3 + 1] * avp[3 + jw]
                 + vl[c * 288 + r * 96 + nw * 3 + 2] * avp[6 + jw];
        size_t gidx = vbase + (size_t)c * HW + off;
        out[gidx] = g * (oh + ov) + x[gidx];
    }
}

extern "C" void kernel_launch(void* const* d_in, const int* in_sizes, int n_in,
                              void* d_out, int out_size, void* d_ws, size_t ws_size,
                              hipStream_t stream) {
    const float* x     = (const float*)d_in[0];
    const float* Wq    = (const float*)d_in[1];
    const float* bq    = (const float*)d_in[2];
    const float* Wk    = (const float*)d_in[3];
    const float* bk    = (const float*)d_in[4];
    const float* Wv    = (const float*)d_in[5];
    const float* bv    = (const float*)d_in[6];
    const float* gamma = (const float*)d_in[7];
    float* out = (float*)d_out;

    u16* xT  = (u16*)d_ws;                                   // B*HW*C bf16  (75.5 MB)
    u16* qws = xT + (size_t)B_ * HW * C_;                    // B*CQ*HW bf16 ( 9.4 MB)
    u16* kws = qws + (size_t)B_ * CQ * HW;                   // B*CQ*HW bf16 ( 9.4 MB)
    // weights buffer aliases the head of xT: xT is dead once the GEMM finishes,
    // and attnw/apply run strictly after it on the same stream.
    float* wbuf = (float*)d_ws;                              // 512*1728 f32 (3.54 MB)

    xpose_kernel<<<dim3(HW / 64, C_ / 64, B_), 256, 0, stream>>>(x, xT);
    qkv_gemm_kernel<<<dim3(HW / 256, 5, B_), 256, 0, stream>>>(
        xT, Wq, bq, Wk, bk, Wv, bv, qws, kws, out);
    attnw_kernel<<<dim3(NBAND, B_), 256, 0, stream>>>(qws, kws, wbuf);
    apply_kernel<<<dim3(C_ / 8, NBAND, B_), 256, 0, stream>>>(x, wbuf, gamma, out);
}

// Round 6
// 414.820 us; speedup vs baseline: 1.5905x; 1.1766x over previous
//
#include <hip/hip_runtime.h>
#include <hip/hip_bf16.h>
#include <cstdint>

#define B_ 16
#define C_ 256
#define CQ 32
#define H_ 96
#define W_ 96
#define HW 9216
#define NBAND 32
#define M_ 320

typedef unsigned short u16;
typedef short bf16x8 __attribute__((ext_vector_type(8)));
typedef float f32x4 __attribute__((ext_vector_type(4)));

__device__ inline u16 f2bf(float f) {
    uint32_t u = __float_as_uint(f);
    u += 0x7FFF + ((u >> 16) & 1);   // RNE
    return (u16)(u >> 16);
}
__device__ inline float bf2f(u16 s) {
    return __uint_as_float(((uint32_t)s) << 16);
}

__device__ inline void gload_lds16(const void* g, void* l) {
    __builtin_amdgcn_global_load_lds(
        (const __attribute__((address_space(1))) uint32_t*)g,
        (__attribute__((address_space(3))) uint32_t*)l, 16, 0, 0);
}

// ---------------- Kernel 0: pack W (f32, split q/k/v) -> Wb bf16 [320][256], biasb f32 [320]
__global__ __launch_bounds__(256) void wpack_kernel(
    const float* __restrict__ Wq, const float* __restrict__ bq,
    const float* __restrict__ Wk, const float* __restrict__ bk,
    const float* __restrict__ Wv, const float* __restrict__ bv,
    u16* __restrict__ Wb, float* __restrict__ biasb)
{
    int m = blockIdx.x;
    int t = threadIdx.x;
    const float* src = (m < 32) ? (Wq + m * 256)
                     : (m < 64) ? (Wk + (m - 32) * 256)
                                : (Wv + (m - 64) * 256);
    Wb[m * 256 + t] = f2bf(src[t]);
    if (t == 0) {
        biasb[m] = (m < 32) ? bq[m] : (m < 64) ? bk[m - 32] : bv[m - 64];
    }
}

// ---------------- Kernel 1: transpose + cast  x[b][c][s] f32 -> xT[b][s][c] bf16
__global__ __launch_bounds__(256) void xpose_kernel(const float* __restrict__ x,
                                                    u16* __restrict__ xT) {
    __shared__ float tile[64][65];
    int s0 = blockIdx.x * 64;
    int c0 = blockIdx.y * 64;
    int b  = blockIdx.z;
    int t = threadIdx.x;

    const float* xb = x + ((size_t)b * C_ + c0) * HW + s0;
    int j = t & 63, i0 = t >> 6;
    #pragma unroll
    for (int ii = 0; ii < 16; ++ii) {
        int i = i0 * 16 + ii;
        tile[i][j] = xb[(size_t)i * HW + j];
    }
    __syncthreads();
    u16* xtb = xT + ((size_t)b * HW + s0) * C_ + c0;
    int i = t & 63, j0 = t >> 6;
    #pragma unroll
    for (int jj = 0; jj < 16; ++jj) {
        int jw = j0 * 16 + jj;
        xtb[(size_t)jw * C_ + i] = f2bf(tile[i][jw]);
    }
}

// ---------------- Kernel 2: qkv GEMM.  out[m][s] = sum_k Wb[m][k] * xT[s][k] + biasb[m]
// BM=320 (all of M), BN=128, BK=64. 512 threads = 8 waves as 2m x 4n.
// LDS rows are 128B (64 bf16); 16B chunk c of row r stored at chunk c^(r&7).
__global__ __launch_bounds__(512, 4) void qkv_gemm_kernel(
    const u16* __restrict__ xT,
    const u16* __restrict__ Wb, const float* __restrict__ biasb,
    u16* __restrict__ qws, u16* __restrict__ kws,
    float* __restrict__ vout)
{
    __shared__ u16 lA[M_ * 64];    // 40 KB
    __shared__ u16 lB[128 * 64];   // 16 KB

    int s0 = blockIdx.x * 128;
    int b  = blockIdx.y;
    int t  = threadIdx.x;
    int w  = t >> 6, l = t & 63;
    int lr = l & 15, lg = l >> 4;
    int wm = w >> 2, wn = w & 3;   // wave tile: rows [wm*160, +160), cols [wn*32, +32)

    f32x4 acc[10][2] = {};

    int rsub = l >> 3;             // row within an 8-row issue group
    int cb   = l & 7;              // chunk within row
    const char* gA = (const char*)Wb;
    const char* gB = (const char*)(xT + ((size_t)b * HW + s0) * C_);

    for (int k0 = 0; k0 < 256; k0 += 64) {
        // stage A: 40 issues (8 rows x 128B each), 5 per wave
        #pragma unroll
        for (int j = 0; j < 5; ++j) {
            int rbase = (w * 5 + j) * 8;
            int r = rbase + rsub;
            const char* src = gA + (size_t)r * 512 + k0 * 2 + ((cb ^ (r & 7)) * 16);
            gload_lds16(src, (char*)lA + rbase * 128);
        }
        // stage B: 16 issues, 2 per wave
        #pragma unroll
        for (int j = 0; j < 2; ++j) {
            int rbase = (w * 2 + j) * 8;
            int r = rbase + rsub;
            const char* src = gB + ((size_t)r * C_ + k0) * 2 + ((cb ^ (r & 7)) * 16);
            gload_lds16(src, (char*)lB + rbase * 128);
        }
        __syncthreads();

        #pragma unroll
        for (int ss = 0; ss < 2; ++ss) {
            int csw = (ss * 4 + lg) ^ (lr & 7);
            bf16x8 bfr[2];
            #pragma unroll
            for (int nf = 0; nf < 2; ++nf) {
                int r = wn * 32 + nf * 16 + lr;
                bfr[nf] = *reinterpret_cast<const bf16x8*>((char*)lB + r * 128 + csw * 16);
            }
            #pragma unroll
            for (int mf = 0; mf < 10; ++mf) {
                int r = wm * 160 + mf * 16 + lr;
                bf16x8 af = *reinterpret_cast<const bf16x8*>((char*)lA + r * 128 + csw * 16);
                acc[mf][0] = __builtin_amdgcn_mfma_f32_16x16x32_bf16(af, bfr[0], acc[mf][0], 0, 0, 0);
                acc[mf][1] = __builtin_amdgcn_mfma_f32_16x16x32_bf16(af, bfr[1], acc[mf][1], 0, 0, 0);
            }
        }
        __syncthreads();
    }

    // epilogue: D row = wm*160 + mf*16 + lg*4 + r, col = s0 + wn*32 + nf*16 + lr
    #pragma unroll
    for (int mf = 0; mf < 10; ++mf) {
        #pragma unroll
        for (int r = 0; r < 4; ++r) {
            int mg = wm * 160 + mf * 16 + lg * 4 + r;
            float bias = biasb[mg];
            #pragma unroll
            for (int nf = 0; nf < 2; ++nf) {
                int s = s0 + wn * 32 + nf * 16 + lr;
                float val = acc[mf][nf][r] + bias;
                if (mg < 32) {
                    qws[((size_t)b * CQ + mg) * HW + s] = f2bf(val);
                } else if (mg < 64) {
                    kws[((size_t)b * CQ + (mg - 32)) * HW + s] = f2bf(val);
                } else {
                    vout[((size_t)b * C_ + (mg - 64)) * HW + s] = val;
                }
            }
        }
    }
}

// ---------------- Kernel 3a: per (b, band) attention weights -> wbuf
// wbuf[(b*32+n)*1728 + 0..863]   = ah[(w*3+kk)*3 + j]
// wbuf[(b*32+n)*1728 + 864..]    = av[(r*32+nw)*9 + kk*3 + jw]
__global__ __launch_bounds__(576) void attnw_kernel(
    const u16* __restrict__ qws, const u16* __restrict__ kws,
    float* __restrict__ wbuf)
{
    __shared__ __align__(16) u16 qkl[2 * CQ * 288];
    int n = blockIdx.x;
    int b = blockIdx.y;
    int t = threadIdx.x;

    u16* ql = qkl;
    u16* kl = qkl + CQ * 288;
    float* gw = wbuf + ((size_t)(b * NBAND + n)) * 1728;

    size_t qbase = (size_t)b * CQ * HW + (size_t)n * 288;   // element index
    // stage q,k as 16B chunks: 1152 chunks per array, 36 chunks per row of 288
    for (int ch = t; ch < 1152; ch += 576) {
        int cq = ch / 36, off = (ch - cq * 36) * 8;
        *reinterpret_cast<uint4*>(&ql[cq * 288 + off]) =
            *reinterpret_cast<const uint4*>(&qws[qbase + (size_t)cq * HW + off]);
        *reinterpret_cast<uint4*>(&kl[cq * 288 + off]) =
            *reinterpret_cast<const uint4*>(&kws[qbase + (size_t)cq * HW + off]);
    }
    __syncthreads();

    int item = t;
    if (item < 288) {
        int w = item % 96, kk = item / 96;
        float l0 = 0.f, l1 = 0.f, l2 = 0.f;
        for (int c = 0; c < CQ; ++c) {
            float qv = bf2f(ql[c * 288 + kk * 96 + w]);
            l0 += qv * bf2f(kl[c * 288 + w]);
            l1 += qv * bf2f(kl[c * 288 + 96 + w]);
            l2 += qv * bf2f(kl[c * 288 + 192 + w]);
        }
        float m = fmaxf(fmaxf(l0, l1), l2);
        float e0 = __expf(l0 - m), e1 = __expf(l1 - m), e2 = __expf(l2 - m);
        float inv = 1.0f / (e0 + e1 + e2);
        gw[(w * 3 + kk) * 3 + 0] = e0 * inv;
        gw[(w * 3 + kk) * 3 + 1] = e1 * inv;
        gw[(w * 3 + kk) * 3 + 2] = e2 * inv;
    } else {
        int it = item - 288;
        int r = it / 96, c2 = it - r * 96;
        int nw = c2 / 3, kk = c2 - nw * 3;
        int base = r * 96 + nw * 3;
        float l0 = 0.f, l1 = 0.f, l2 = 0.f;
        for (int c = 0; c < CQ; ++c) {
            float qv = bf2f(ql[c * 288 + base + kk]);
            l0 += qv * bf2f(kl[c * 288 + base + 0]);
            l1 += qv * bf2f(kl[c * 288 + base + 1]);
            l2 += qv * bf2f(kl[c * 288 + base + 2]);
        }
        float m = fmaxf(fmaxf(l0, l1), l2);
        float e0 = __expf(l0 - m), e1 = __expf(l1 - m), e2 = __expf(l2 - m);
        float inv = 1.0f / (e0 + e1 + e2);
        float* avp = gw + 864 + (r * 32 + nw) * 9 + kk * 3;
        avp[0] = e0 * inv;
        avp[1] = e1 * inv;
        avp[2] = e2 * inv;
    }
}

// ---------------- Kernel 3b: apply. One block per (b, band, 64-channel chunk).
// Thread owns (channel, nw 3-col group); 3x3 v/x patch in registers; weights hoisted.
__global__ __launch_bounds__(256) void apply_kernel(
    const float* __restrict__ x,
    const float* __restrict__ wbuf,
    const float* __restrict__ gamma,
    float* __restrict__ out)   // holds v on entry for this block's region
{
    __shared__ float wsh[1728];     // ah [0,864), av [864,1728)
    int cc = blockIdx.x;            // 64-channel chunk
    int n  = blockIdx.y;
    int b  = blockIdx.z;
    int t  = threadIdx.x;
    float g = gamma[0];

    const float* gw = wbuf + ((size_t)(b * NBAND + n)) * 1728;
    for (int e = t; e < 432; e += 256)
        reinterpret_cast<float4*>(wsh)[e] = reinterpret_cast<const float4*>(gw)[e];
    __syncthreads();

    int lane = t & 63;
    int nw   = lane & 31;
    int half = lane >> 5;
    int wv   = t >> 6;

    // hoist weights: wa[jw][k][r] = ah[(nw*3+jw)*9 + k*3 + r]
    //                wb[r][k][jw] = av[(r*32+nw)*9 + k*3 + jw]
    float wa[3][3][3], wb[3][3][3];
    #pragma unroll
    for (int jw = 0; jw < 3; ++jw)
        #pragma unroll
        for (int k = 0; k < 3; ++k)
            #pragma unroll
            for (int r = 0; r < 3; ++r)
                wa[jw][k][r] = wsh[(nw * 3 + jw) * 9 + k * 3 + r];
    #pragma unroll
    for (int r = 0; r < 3; ++r)
        #pragma unroll
        for (int k = 0; k < 3; ++k)
            #pragma unroll
            for (int jw = 0; jw < 3; ++jw)
                wb[r][k][jw] = wsh[864 + (r * 32 + nw) * 9 + k * 3 + jw];

    #pragma unroll
    for (int i = 0; i < 8; ++i) {
        int c = cc * 64 + wv * 16 + i * 2 + half;
        size_t base = ((size_t)b * C_ + c) * HW + (size_t)n * 288 + nw * 3;
        float v[3][3], xr[3][3];
        #pragma unroll
        for (int r = 0; r < 3; ++r) {
            #pragma unroll
            for (int jw = 0; jw < 3; ++jw) {
                v[r][jw]  = out[base + r * 96 + jw];
                xr[r][jw] = x[base + r * 96 + jw];
            }
        }
        #pragma unroll
        for (int r = 0; r < 3; ++r) {
            #pragma unroll
            for (int jw = 0; jw < 3; ++jw) {
                float oh = v[0][jw] * wa[jw][0][r]
                         + v[1][jw] * wa[jw][1][r]
                         + v[2][jw] * wa[jw][2][r];
                float ov = v[r][0] * wb[r][0][jw]
                         + v[r][1] * wb[r][1][jw]
                         + v[r][2] * wb[r][2][jw];
                out[base + r * 96 + jw] = g * (oh + ov) + xr[r][jw];
            }
        }
    }
}

extern "C" void kernel_launch(void* const* d_in, const int* in_sizes, int n_in,
                              void* d_out, int out_size, void* d_ws, size_t ws_size,
                              hipStream_t stream) {
    const float* x     = (const float*)d_in[0];
    const float* Wq    = (const float*)d_in[1];
    const float* bq    = (const float*)d_in[2];
    const float* Wk    = (const float*)d_in[3];
    const float* bk    = (const float*)d_in[4];
    const float* Wv    = (const float*)d_in[5];
    const float* bv    = (const float*)d_in[6];
    const float* gamma = (const float*)d_in[7];
    float* out = (float*)d_out;

    u16* xT    = (u16*)d_ws;                                 // B*HW*C bf16  (75.5 MB)
    u16* qws   = xT + (size_t)B_ * HW * C_;                  // B*CQ*HW bf16 ( 9.4 MB)
    u16* kws   = qws + (size_t)B_ * CQ * HW;                 // B*CQ*HW bf16 ( 9.4 MB)
    u16* Wb    = kws + (size_t)B_ * CQ * HW;                 // 320*256 bf16 (160 KB)
    float* biasb = (float*)(Wb + (size_t)M_ * 256);          // 320 f32
    // weights buffer aliases the head of xT: xT is dead once the GEMM finishes.
    float* wbuf = (float*)d_ws;                              // 512*1728 f32 (3.54 MB)

    wpack_kernel<<<dim3(M_), 256, 0, stream>>>(Wq, bq, Wk, bk, Wv, bv, Wb, biasb);
    xpose_kernel<<<dim3(HW / 64, C_ / 64, B_), 256, 0, stream>>>(x, xT);
    qkv_gemm_kernel<<<dim3(HW / 128, B_), 512, 0, stream>>>(
        xT, Wb, biasb, qws, kws, out);
    attnw_kernel<<<dim3(NBAND, B_), 576, 0, stream>>>(qws, kws, wbuf);
    apply_kernel<<<dim3(C_ / 64, NBAND, B_), 256, 0, stream>>>(x, wbuf, gamma, out);
}

// Round 8
// 378.960 us; speedup vs baseline: 1.7410x; 1.0946x over previous
//
#include <hip/hip_runtime.h>
#include <hip/hip_bf16.h>
#include <cstdint>

#define B_ 16
#define C_ 256
#define CQ 32
#define H_ 96
#define W_ 96
#define HW 9216
#define NBAND 32
#define M_ 320

typedef unsigned short u16;
typedef short bf16x8 __attribute__((ext_vector_type(8)));
typedef float f32x4 __attribute__((ext_vector_type(4)));

__device__ inline u16 f2bf(float f) {
    uint32_t u = __float_as_uint(f);
    u += 0x7FFF + ((u >> 16) & 1);   // RNE
    return (u16)(u >> 16);
}
__device__ inline float bf2f(u16 s) {
    return __uint_as_float(((uint32_t)s) << 16);
}

__device__ inline void gload_lds16(const void* g, void* l) {
    __builtin_amdgcn_global_load_lds(
        (const __attribute__((address_space(1))) uint32_t*)g,
        (__attribute__((address_space(3))) uint32_t*)l, 16, 0, 0);
}

// ---------------- Kernel 0: pack W (f32, split q/k/v) -> Wb bf16 [320][256], biasb f32 [320]
__global__ __launch_bounds__(256) void wpack_kernel(
    const float* __restrict__ Wq, const float* __restrict__ bq,
    const float* __restrict__ Wk, const float* __restrict__ bk,
    const float* __restrict__ Wv, const float* __restrict__ bv,
    u16* __restrict__ Wb, float* __restrict__ biasb)
{
    int m = blockIdx.x;
    int t = threadIdx.x;
    const float* src = (m < 32) ? (Wq + m * 256)
                     : (m < 64) ? (Wk + (m - 32) * 256)
                                : (Wv + (m - 64) * 256);
    Wb[m * 256 + t] = f2bf(src[t]);
    if (t == 0) {
        biasb[m] = (m < 32) ? bq[m] : (m < 64) ? bk[m - 32] : bv[m - 64];
    }
}

// ---------------- Kernel 1: transpose + cast  x[b][c][s] f32 -> xT[b][s][c] bf16
// float4 loads; paired-bf16 uint stores (full-rate).
__global__ __launch_bounds__(256) void xpose_kernel(const float* __restrict__ x,
                                                    u16* __restrict__ xT) {
    __shared__ float tile[64][65];
    int s0 = blockIdx.x * 64;
    int c0 = blockIdx.y * 64;
    int b  = blockIdx.z;
    int t = threadIdx.x;

    const float* xb = x + ((size_t)b * C_ + c0) * HW + s0;
    {
        int jj = (t & 15) * 4;      // col (s) within tile
        int i0 = t >> 4;            // 16 row groups of 4
        #pragma unroll
        for (int r = 0; r < 4; ++r) {
            int i = i0 * 4 + r;
            float4 f = *reinterpret_cast<const float4*>(&xb[(size_t)i * HW + jj]);
            tile[i][jj + 0] = f.x;
            tile[i][jj + 1] = f.y;
            tile[i][jj + 2] = f.z;
            tile[i][jj + 3] = f.w;
        }
    }
    __syncthreads();
    u16* xtb = xT + ((size_t)b * HW + s0) * C_ + c0;
    {
        int i2 = (t & 31) * 2;      // c-pair
        int j0 = t >> 5;            // 8 col groups of 8
        #pragma unroll
        for (int jj = 0; jj < 8; ++jj) {
            int jw = j0 * 8 + jj;
            uint32_t p = (uint32_t)f2bf(tile[i2][jw])
                       | ((uint32_t)f2bf(tile[i2 + 1][jw]) << 16);
            *reinterpret_cast<uint32_t*>(&xtb[(size_t)jw * C_ + i2]) = p;
        }
    }
}

// ---------------- Kernel 2: qkv GEMM.  out[m][s] = sum_k Wb[m][k] * xT[s][k] + biasb[m]
// BM=320 (all of M), BN=128, BK=64. 512 threads = 8 waves as 2m x 4n.
// LDS rows are 128B (64 bf16); 16B chunk c of row r stored at chunk c^(r&7).
// q,k,v all written as bf16 to ws.
__global__ __launch_bounds__(512, 4) void qkv_gemm_kernel(
    const u16* __restrict__ xT,
    const u16* __restrict__ Wb, const float* __restrict__ biasb,
    u16* __restrict__ qws, u16* __restrict__ kws,
    u16* __restrict__ vws)
{
    __shared__ u16 lA[M_ * 64];    // 40 KB
    __shared__ u16 lB[128 * 64];   // 16 KB

    int s0 = blockIdx.x * 128;
    int b  = blockIdx.y;
    int t  = threadIdx.x;
    int w  = t >> 6, l = t & 63;
    int lr = l & 15, lg = l >> 4;
    int wm = w >> 2, wn = w & 3;   // wave tile: rows [wm*160, +160), cols [wn*32, +32)

    f32x4 acc[10][2] = {};

    int rsub = l >> 3;             // row within an 8-row issue group
    int cb   = l & 7;              // chunk within row
    const char* gA = (const char*)Wb;
    const char* gB = (const char*)(xT + ((size_t)b * HW + s0) * C_);

    for (int k0 = 0; k0 < 256; k0 += 64) {
        // stage A: 40 issues (8 rows x 128B each), 5 per wave
        #pragma unroll
        for (int j = 0; j < 5; ++j) {
            int rbase = (w * 5 + j) * 8;
            int r = rbase + rsub;
            const char* src = gA + (size_t)r * 512 + k0 * 2 + ((cb ^ (r & 7)) * 16);
            gload_lds16(src, (char*)lA + rbase * 128);
        }
        // stage B: 16 issues, 2 per wave
        #pragma unroll
        for (int j = 0; j < 2; ++j) {
            int rbase = (w * 2 + j) * 8;
            int r = rbase + rsub;
            const char* src = gB + ((size_t)r * C_ + k0) * 2 + ((cb ^ (r & 7)) * 16);
            gload_lds16(src, (char*)lB + rbase * 128);
        }
        __syncthreads();

        #pragma unroll
        for (int ss = 0; ss < 2; ++ss) {
            int csw = (ss * 4 + lg) ^ (lr & 7);
            bf16x8 bfr[2];
            #pragma unroll
            for (int nf = 0; nf < 2; ++nf) {
                int r = wn * 32 + nf * 16 + lr;
                bfr[nf] = *reinterpret_cast<const bf16x8*>((char*)lB + r * 128 + csw * 16);
            }
            #pragma unroll
            for (int mf = 0; mf < 10; ++mf) {
                int r = wm * 160 + mf * 16 + lr;
                bf16x8 af = *reinterpret_cast<const bf16x8*>((char*)lA + r * 128 + csw * 16);
                acc[mf][0] = __builtin_amdgcn_mfma_f32_16x16x32_bf16(af, bfr[0], acc[mf][0], 0, 0, 0);
                acc[mf][1] = __builtin_amdgcn_mfma_f32_16x16x32_bf16(af, bfr[1], acc[mf][1], 0, 0, 0);
            }
        }
        __syncthreads();
    }

    // epilogue: D row = wm*160 + mf*16 + lg*4 + r, col = s0 + wn*32 + nf*16 + lr
    #pragma unroll
    for (int mf = 0; mf < 10; ++mf) {
        #pragma unroll
        for (int r = 0; r < 4; ++r) {
            int mg = wm * 160 + mf * 16 + lg * 4 + r;
            float bias = biasb[mg];
            #pragma unroll
            for (int nf = 0; nf < 2; ++nf) {
                int s = s0 + wn * 32 + nf * 16 + lr;
                float val = acc[mf][nf][r] + bias;
                if (mg < 32) {
                    qws[((size_t)b * CQ + mg) * HW + s] = f2bf(val);
                } else if (mg < 64) {
                    kws[((size_t)b * CQ + (mg - 32)) * HW + s] = f2bf(val);
                } else {
                    vws[((size_t)b * C_ + (mg - 64)) * HW + s] = f2bf(val);
                }
            }
        }
    }
}

// ---------------- Kernel 3a: per (b, band) attention weights -> wbuf
// wbuf[(b*32+n)*1728 + 0..863]   = ah[(w*3+kk)*3 + j]
// wbuf[(b*32+n)*1728 + 864..]    = av[(r*32+nw)*9 + kk*3 + jw]
__global__ __launch_bounds__(576) void attnw_kernel(
    const u16* __restrict__ qws, const u16* __restrict__ kws,
    float* __restrict__ wbuf)
{
    __shared__ __align__(16) u16 qkl[2 * CQ * 288];
    int n = blockIdx.x;
    int b = blockIdx.y;
    int t = threadIdx.x;

    u16* ql = qkl;
    u16* kl = qkl + CQ * 288;
    float* gw = wbuf + ((size_t)(b * NBAND + n)) * 1728;

    size_t qbase = (size_t)b * CQ * HW + (size_t)n * 288;   // element index
    // stage q,k as 16B chunks: 1152 chunks per array, 36 chunks per row of 288
    for (int ch = t; ch < 1152; ch += 576) {
        int cq = ch / 36, off = (ch - cq * 36) * 8;
        *reinterpret_cast<uint4*>(&ql[cq * 288 + off]) =
            *reinterpret_cast<const uint4*>(&qws[qbase + (size_t)cq * HW + off]);
        *reinterpret_cast<uint4*>(&kl[cq * 288 + off]) =
            *reinterpret_cast<const uint4*>(&kws[qbase + (size_t)cq * HW + off]);
    }
    __syncthreads();

    int item = t;
    if (item < 288) {
        int w = item % 96, kk = item / 96;
        float l0 = 0.f, l1 = 0.f, l2 = 0.f;
        for (int c = 0; c < CQ; ++c) {
            float qv = bf2f(ql[c * 288 + kk * 96 + w]);
            l0 += qv * bf2f(kl[c * 288 + w]);
            l1 += qv * bf2f(kl[c * 288 + 96 + w]);
            l2 += qv * bf2f(kl[c * 288 + 192 + w]);
        }
        float m = fmaxf(fmaxf(l0, l1), l2);
        float e0 = __expf(l0 - m), e1 = __expf(l1 - m), e2 = __expf(l2 - m);
        float inv = 1.0f / (e0 + e1 + e2);
        gw[(w * 3 + kk) * 3 + 0] = e0 * inv;
        gw[(w * 3 + kk) * 3 + 1] = e1 * inv;
        gw[(w * 3 + kk) * 3 + 2] = e2 * inv;
    } else {
        int it = item - 288;
        int r = it / 96, c2 = it - r * 96;
        int nw = c2 / 3, kk = c2 - nw * 3;
        int base = r * 96 + nw * 3;
        float l0 = 0.f, l1 = 0.f, l2 = 0.f;
        for (int c = 0; c < CQ; ++c) {
            float qv = bf2f(ql[c * 288 + base + kk]);
            l0 += qv * bf2f(kl[c * 288 + base + 0]);
            l1 += qv * bf2f(kl[c * 288 + base + 1]);
            l2 += qv * bf2f(kl[c * 288 + base + 2]);
        }
        float m = fmaxf(fmaxf(l0, l1), l2);
        float e0 = __expf(l0 - m), e1 = __expf(l1 - m), e2 = __expf(l2 - m);
        float inv = 1.0f / (e0 + e1 + e2);
        float* avp = gw + 864 + (r * 32 + nw) * 9 + kk * 3;
        avp[0] = e0 * inv;
        avp[1] = e1 * inv;
        avp[2] = e2 * inv;
    }
}

// ---------------- Kernel 3b: apply. One block per (b, band, 64-channel chunk).
// Thread owns (channel, nw 3-col group); 3x3 v(bf16)/x patch in registers; weights hoisted.
__global__ __launch_bounds__(256) void apply_kernel(
    const float* __restrict__ x,
    const u16* __restrict__ vws,
    const float* __restrict__ wbuf,
    const float* __restrict__ gamma,
    float* __restrict__ out)
{
    __shared__ float wsh[1728];     // ah [0,864), av [864,1728)
    int cc = blockIdx.x;            // 64-channel chunk
    int n  = blockIdx.y;
    int b  = blockIdx.z;
    int t  = threadIdx.x;
    float g = gamma[0];

    const float* gw = wbuf + ((size_t)(b * NBAND + n)) * 1728;
    for (int e = t; e < 432; e += 256)
        reinterpret_cast<float4*>(wsh)[e] = reinterpret_cast<const float4*>(gw)[e];
    __syncthreads();

    int lane = t & 63;
    int nw   = lane & 31;
    int half = lane >> 5;
    int wv   = t >> 6;

    // hoist weights: wa[jw][k][r] = ah[(nw*3+jw)*9 + k*3 + r]
    //                wb[r][k][jw] = av[(r*32+nw)*9 + k*3 + jw]
    float wa[3][3][3], wb[3][3][3];
    #pragma unroll
    for (int jw = 0; jw < 3; ++jw)
        #pragma unroll
        for (int k = 0; k < 3; ++k)
            #pragma unroll
            for (int r = 0; r < 3; ++r)
                wa[jw][k][r] = wsh[(nw * 3 + jw) * 9 + k * 3 + r];
    #pragma unroll
    for (int r = 0; r < 3; ++r)
        #pragma unroll
        for (int k = 0; k < 3; ++k)
            #pragma unroll
            for (int jw = 0; jw < 3; ++jw)
                wb[r][k][jw] = wsh[864 + (r * 32 + nw) * 9 + k * 3 + jw];

    #pragma unroll
    for (int i = 0; i < 8; ++i) {
        int c = cc * 64 + wv * 16 + i * 2 + half;
        size_t base  = ((size_t)b * C_ + c) * HW + (size_t)n * 288 + nw * 3;
        const u16* vp = vws + base;
        float v[3][3], xr[3][3];
        #pragma unroll
        for (int r = 0; r < 3; ++r) {
            #pragma unroll
            for (int jw = 0; jw < 3; ++jw) {
                v[r][jw]  = bf2f(vp[r * 96 + jw]);
                xr[r][jw] = x[base + r * 96 + jw];
            }
        }
        #pragma unroll
        for (int r = 0; r < 3; ++r) {
            #pragma unroll
            for (int jw = 0; jw < 3; ++jw) {
                float oh = v[0][jw] * wa[jw][0][r]
                         + v[1][jw] * wa[jw][1][r]
                         + v[2][jw] * wa[jw][2][r];
                float ov = v[r][0] * wb[r][0][jw]
                         + v[r][1] * wb[r][1][jw]
                         + v[r][2] * wb[r][2][jw];
                out[base + r * 96 + jw] = g * (oh + ov) + xr[r][jw];
            }
        }
    }
}

extern "C" void kernel_launch(void* const* d_in, const int* in_sizes, int n_in,
                              void* d_out, int out_size, void* d_ws, size_t ws_size,
                              hipStream_t stream) {
    const float* x     = (const float*)d_in[0];
    const float* Wq    = (const float*)d_in[1];
    const float* bq    = (const float*)d_in[2];
    const float* Wk    = (const float*)d_in[3];
    const float* bk    = (const float*)d_in[4];
    const float* Wv    = (const float*)d_in[5];
    const float* bv    = (const float*)d_in[6];
    const float* gamma = (const float*)d_in[7];
    float* out = (float*)d_out;

    u16* xT    = (u16*)d_ws;                                 // B*HW*C bf16  (75.5 MB)
    u16* qws   = xT + (size_t)B_ * HW * C_;                  // B*CQ*HW bf16 ( 9.4 MB)
    u16* kws   = qws + (size_t)B_ * CQ * HW;                 // B*CQ*HW bf16 ( 9.4 MB)
    u16* vws   = kws + (size_t)B_ * CQ * HW;                 // B*C*HW  bf16 (75.5 MB)
    u16* Wb    = vws + (size_t)B_ * C_ * HW;                 // 320*256 bf16 (160 KB)
    float* biasb = (float*)(Wb + (size_t)M_ * 256);          // 320 f32
    // weights buffer aliases the head of xT: xT is dead once the GEMM finishes.
    float* wbuf = (float*)d_ws;                              // 512*1728 f32 (3.54 MB)

    wpack_kernel<<<dim3(M_), 256, 0, stream>>>(Wq, bq, Wk, bk, Wv, bv, Wb, biasb);
    xpose_kernel<<<dim3(HW / 64, C_ / 64, B_), 256, 0, stream>>>(x, xT);
    qkv_gemm_kernel<<<dim3(HW / 128, B_), 512, 0, stream>>>(
        xT, Wb, biasb, qws, kws, vws);
    attnw_kernel<<<dim3(NBAND, B_), 576, 0, stream>>>(qws, kws, wbuf);
    apply_kernel<<<dim3(C_ / 64, NBAND, B_), 256, 0, stream>>>(x, vws, wbuf, gamma, out);
}